// Round 6
// baseline (190.056 us; speedup 1.0000x reference)
//
#include <hip/hip_runtime.h>
#include <hip/hip_bf16.h>

// STPT-Light: x->(Q,K,V) proj (fused K-norm+rho), fused chunked linear-attn, out proj.
// B=4 T=1024 D=1024 H=16 DK=64. Chunk C=64, 16 chunks, 64 (b,h) pairs.
//
// ws layout (MB): 0 x_b[8] | 8 Wq_b[2] 10 Wk_b[2] 12 Wv_b[2] 14 Wo_b[2]
//   16 Qb[8] 24 Kb[8] 32 Vb[8] 40 Yb[8]  (bf16 4096x1024)
//   72 rho[256KB f32]

typedef __bf16 b16x8 __attribute__((ext_vector_type(8)));
typedef float  f32x4 __attribute__((ext_vector_type(4)));
typedef unsigned short u16x8 __attribute__((ext_vector_type(8)));
using bf16_t = __hip_bfloat16;

#define AS1C(p) ((const __attribute__((address_space(1))) void*)(p))
#define AS3(p)  ((__attribute__((address_space(3))) void*)(p))

__device__ __forceinline__ void g2l16(const void* g, void* l) {
  __builtin_amdgcn_global_load_lds(AS1C(g), AS3(l), 16, 0, 0);
}

__device__ __forceinline__ unsigned short f2b(float x) {  // RNE f32->bf16 bits
  unsigned u = __float_as_uint(x);
  return (unsigned short)((u + 0x7FFFu + ((u >> 16) & 1u)) >> 16);
}
__device__ __forceinline__ float b2f(unsigned short b) {
  return __uint_as_float(((unsigned)b) << 16);
}

// Wire-format detector: f32 N(0,1) words have exponent field in [95,135].
__device__ __forceinline__ int wire_flag(const unsigned* __restrict__ x, int tid) {
  unsigned u = x[tid & 63];
  int e = (int)((u >> 23) & 0xFF);
  unsigned long long m = __ballot(e >= 95 && e <= 135);
  return (__popcll(m) >= 32) ? 1 : 0;   // 1 = f32 wire
}

// ---------------------------------------------------------------------------
// Fused conversion of all 5 input tensors to bf16 (or passthrough copy).
// ---------------------------------------------------------------------------
__global__ __launch_bounds__(256)
void convert_all(const void* __restrict__ x,
                 const void* __restrict__ w0, const void* __restrict__ w1,
                 const void* __restrict__ w2, const void* __restrict__ w3,
                 unsigned short* __restrict__ xb,
                 unsigned short* __restrict__ wb0, unsigned short* __restrict__ wb1,
                 unsigned short* __restrict__ wb2, unsigned short* __restrict__ wb3)
{
  const int fm = wire_flag((const unsigned*)x, threadIdx.x);
  const long i8 = ((long)blockIdx.x * 256 + threadIdx.x) * 8;
  const void* src; unsigned short* dst; long off;
  if (i8 < 4194304) { src = x; dst = xb; off = i8; }
  else {
    long j = i8 - 4194304;
    int w = (int)(j >> 20); off = j & 1048575;
    src = (w == 0) ? w0 : (w == 1) ? w1 : (w == 2) ? w2 : w3;
    dst = (w == 0) ? wb0 : (w == 1) ? wb1 : (w == 2) ? wb2 : wb3;
  }
  if (fm) {
    const float4 a = *(const float4*)((const float*)src + off);
    const float4 b = *(const float4*)((const float*)src + off + 4);
    u16x8 o;
    o[0] = f2b(a.x); o[1] = f2b(a.y); o[2] = f2b(a.z); o[3] = f2b(a.w);
    o[4] = f2b(b.x); o[5] = f2b(b.y); o[6] = f2b(b.z); o[7] = f2b(b.w);
    *(u16x8*)(dst + off) = o;
  } else {
    *(int4*)(dst + off) = *(const int4*)((const unsigned short*)src + off);
  }
}

// ---------------------------------------------------------------------------
// Fused Q/K/V projection. 128x128 tile, BK=64 (32 MFMA per barrier pair),
// XOR source swizzle, XCD patch decode. z==1 (K): epilogue L2-norm + rho.
// ---------------------------------------------------------------------------
__global__ __launch_bounds__(256)
void gemm_qkv(const unsigned* __restrict__ xraw,
              const bf16_t* __restrict__ A,
              const bf16_t* __restrict__ B0, const bf16_t* __restrict__ B1,
              const bf16_t* __restrict__ B2,
              unsigned short* __restrict__ C0, unsigned short* __restrict__ C1,
              unsigned short* __restrict__ C2,
              const void* __restrict__ Wg, const void* __restrict__ bg,
              const void* __restrict__ Wl, const void* __restrict__ bl,
              float* __restrict__ rho)
{
  constexpr int K = 1024, N = 1024;
  const int flat = blockIdx.x;
  const int xcd = flat & 7, sl = flat >> 3;
  const int z = sl >> 5, t5 = sl & 31;
  const int bx = ((xcd & 1) << 2) | (t5 & 3);
  const int by = ((xcd >> 1) << 3) | (t5 >> 2);
  const bf16_t* B = (z == 0) ? B0 : (z == 1) ? B1 : B2;
  unsigned short* C = (z == 0) ? C0 : (z == 1) ? C1 : C2;
  __shared__ __align__(16) unsigned short As[128 * 64];
  __shared__ __align__(16) unsigned short Bs[128 * 64];
  const int tid  = threadIdx.x;
  const int lane = tid & 63;
  const int wave = tid >> 6;
  const int wm = wave >> 1, wn = wave & 1;
  const int quad = lane >> 4, tm = lane & 15;
  const long row0 = (long)by * 128;
  const long col0 = (long)bx * 128;

  f32x4 acc[4][4];
#pragma unroll
  for (int i = 0; i < 4; ++i)
#pragma unroll
    for (int j = 0; j < 4; ++j) acc[i][j] = (f32x4){0.f, 0.f, 0.f, 0.f};

  // staging: idx = shot*256+tid; row = idx>>3 (64 cols = 8 chunks of 8 u16)
  const int sr = tid >> 3;            // 0..31 (+32/shot)
  const int c2 = tid & 7;
  const int gc = c2 ^ (sr & 7);       // (row&7) == (sr&7) since shots add 32
  const bf16_t* ap = A + (row0 + sr) * (long)K + gc * 8;
  const bf16_t* bp = B + (col0 + sr) * (long)K + gc * 8;
  unsigned short* la = As + tid * 8;
  unsigned short* lb = Bs + tid * 8;

  for (int kt = 0; kt < K; kt += 64) {
    __syncthreads();
#pragma unroll
    for (int sh = 0; sh < 4; ++sh) {
      g2l16(ap + (long)sh * 32 * K + kt, la + sh * 2048);
      g2l16(bp + (long)sh * 32 * K + kt, lb + sh * 2048);
    }
    __syncthreads();

#pragma unroll
    for (int kk = 0; kk < 2; ++kk) {
      const int pcsel = ((kk * 4 + quad) ^ (tm & 7)) << 3;
      b16x8 af[4], bfr[4];
#pragma unroll
      for (int i = 0; i < 4; ++i)
        af[i] = *(const b16x8*)&As[(wm * 64 + i * 16 + tm) * 64 + pcsel];
#pragma unroll
      for (int j = 0; j < 4; ++j)
        bfr[j] = *(const b16x8*)&Bs[(wn * 64 + j * 16 + tm) * 64 + pcsel];
#pragma unroll
      for (int i = 0; i < 4; ++i)
#pragma unroll
        for (int j = 0; j < 4; ++j)
          acc[i][j] = __builtin_amdgcn_mfma_f32_16x16x32_bf16(af[i], bfr[j], acc[i][j], 0, 0, 0);
    }
  }

  if (z != 1) {
#pragma unroll
    for (int i = 0; i < 4; ++i)
#pragma unroll
      for (int j = 0; j < 4; ++j)
#pragma unroll
        for (int r = 0; r < 4; ++r) {
          long row = row0 + wm * 64 + i * 16 + quad * 4 + r;
          long col = col0 + wn * 64 + j * 16 + tm;
          C[row * N + col] = f2b(acc[i][j][r]);
        }
  } else {
    const int fm = wire_flag(xraw, tid);
    const int h = bx * 2 + wn;
    float wgv, bgv, wlv, blv;
    if (fm) {
      wgv = ((const float*)Wg)[h]; bgv = ((const float*)bg)[h];
      wlv = ((const float*)Wl)[h]; blv = ((const float*)bl)[h];
    } else {
      wgv = b2f(((const unsigned short*)Wg)[h]); bgv = b2f(((const unsigned short*)bg)[h]);
      wlv = b2f(((const unsigned short*)Wl)[h]); blv = b2f(((const unsigned short*)bl)[h]);
    }
#pragma unroll
    for (int i = 0; i < 4; ++i)
#pragma unroll
      for (int r = 0; r < 4; ++r) {
        float ss = 0.f, sv = 0.f;
#pragma unroll
        for (int j = 0; j < 4; ++j) {
          const float v = acc[i][j][r];
          ss += v * v; sv += v;
        }
#pragma unroll
        for (int m = 1; m < 16; m <<= 1) {
          ss += __shfl_xor(ss, m);
          sv += __shfl_xor(sv, m);
        }
        const float inv = 1.f / fmaxf(sqrtf(ss), 1e-12f);
        const long row = row0 + wm * 64 + i * 16 + quad * 4 + r;
#pragma unroll
        for (int j = 0; j < 4; ++j)
          C[row * N + col0 + wn * 64 + j * 16 + tm] = f2b(acc[i][j][r] * inv);
        if (tm == 0) {
          const float kbar = sv * inv * (1.f / 64.f);
          const float gm = 1.f / (1.f + expf(-(wgv * kbar + bgv)));
          const float lm = 1.f / (1.f + expf(-(wlv * kbar + blv)));
          const int b = (int)(row >> 10), t = (int)(row & 1023);
          rho[(size_t)(b * 16 + h) * 1024 + t] = (1.f - lm) * gm;
        }
      }
  }
}

// ---------------------------------------------------------------------------
// Output GEMM: 64x64 tile, BK=64, XCD patch decode.
// ---------------------------------------------------------------------------
__global__ __launch_bounds__(256)
void gemm_out64(const unsigned* __restrict__ xraw,
                const bf16_t* __restrict__ A, const bf16_t* __restrict__ B,
                void* __restrict__ C)
{
  constexpr int K = 1024, N = 1024;
  const int flat = blockIdx.x;
  const int xcd = flat & 7, sl = flat >> 3;
  const int bx = sl & 15;
  const int by = (xcd << 3) | (sl >> 4);
  __shared__ __align__(16) unsigned short As[64 * 64];
  __shared__ __align__(16) unsigned short Bs[64 * 64];
  const int tid  = threadIdx.x;
  const int lane = tid & 63;
  const int wave = tid >> 6;
  const int quad = lane >> 4, tm = lane & 15;
  const long row0 = (long)by * 64;
  const long col0 = (long)bx * 64;

  f32x4 acc[4];
#pragma unroll
  for (int i = 0; i < 4; ++i) acc[i] = (f32x4){0.f, 0.f, 0.f, 0.f};

  const int sr = tid >> 2;
  const int scc = tid & 3;
  const int qg = (scc - (sr >> 1)) & 3;
  const bf16_t* ap = A + (row0 + sr) * (long)K + qg * 8;
  const bf16_t* bp = B + (col0 + sr) * (long)K + qg * 8;
  unsigned short* la = As + tid * 8;
  unsigned short* lb = Bs + tid * 8;
  const int cc = (quad + ((tm >> 1) & 3)) & 3;

  for (int kt = 0; kt < K; kt += 64) {
    __syncthreads();
    g2l16(ap + kt,      la);
    g2l16(ap + kt + 32, la + 2048);
    g2l16(bp + kt,      lb);
    g2l16(bp + kt + 32, lb + 2048);
    __syncthreads();

    b16x8 bf0 = *(const b16x8*)&Bs[(wave * 16 + tm) * 32 + cc * 8];
    b16x8 bf1 = *(const b16x8*)&Bs[2048 + (wave * 16 + tm) * 32 + cc * 8];
#pragma unroll
    for (int i = 0; i < 4; ++i) {
      b16x8 a0 = *(const b16x8*)&As[(i * 16 + tm) * 32 + cc * 8];
      b16x8 a1 = *(const b16x8*)&As[2048 + (i * 16 + tm) * 32 + cc * 8];
      acc[i] = __builtin_amdgcn_mfma_f32_16x16x32_bf16(a0, bf0, acc[i], 0, 0, 0);
      acc[i] = __builtin_amdgcn_mfma_f32_16x16x32_bf16(a1, bf1, acc[i], 0, 0, 0);
    }
  }

  const int fm = wire_flag(xraw, tid);
#pragma unroll
  for (int i = 0; i < 4; ++i)
#pragma unroll
    for (int r = 0; r < 4; ++r) {
      const long row = row0 + i * 16 + quad * 4 + r;
      const long col = col0 + wave * 16 + tm;
      const float v = acc[i][r];
      if (fm) ((float*)C)[row * N + col] = v;
      else    ((unsigned short*)C)[row * N + col] = f2b(v);
    }
}

// ---------------------------------------------------------------------------
// XOR-swizzled chunk staging + reads (from R5; conflict-free).
// ---------------------------------------------------------------------------
__device__ __forceinline__ void stage_chunk_x(const unsigned short* G, int n0c, int h,
                                              unsigned short* lds, int tid) {
#pragma unroll
  for (int sh = 0; sh < 2; ++sh) {
    const int idx = sh * 256 + tid;
    const int row = idx >> 3, c2 = idx & 7;
    const int gc = c2 ^ (row & 7);
    g2l16(G + (size_t)(n0c + row) * 1024 + h * 64 + gc * 8, lds + idx * 8);
  }
}
__device__ __forceinline__ b16x8 rdx(const unsigned short* lds, int row, int k0) {
  return *(const b16x8*)&lds[row * 64 + (((k0 >> 3) ^ (row & 7)) << 3)];
}
__device__ __forceinline__ float rdx1(const unsigned short* lds, int row, int col) {
  return b2f(lds[row * 64 + (((col >> 3) ^ (row & 7)) << 3) + (col & 7)]);
}

// dst[col][row] (stride 72 bf16) from XOR-staged src[row][col].
__device__ __forceinline__ void transpose_x(const unsigned short* src,
                                            unsigned short* dst, int tid) {
  const int kc = tid & 63;
  const int s4 = (tid >> 6) * 16;
  u16x8 o0, o1;
#pragma unroll
  for (int i = 0; i < 16; ++i) {
    const unsigned short b = f2b(rdx1(src, s4 + i, kc));
    if (i < 8) o0[i] = b; else o1[i - 8] = b;
  }
  *(u16x8*)&dst[kc * 72 + s4]     = o0;
  *(u16x8*)&dst[kc * 72 + s4 + 8] = o1;
}

// ---------------------------------------------------------------------------
// Fused chunked scan: one block per (b,h); 16 sequential chunks with DMA
// prefetch. S^T carried in f32 regs (C-layout ownership) + bf16 LDS shadow.
// Per chunk: P=QV^T masked; Y = Pw*K + a_t*Q*S_prev; U = Ktilde^T*V; S update.
// ---------------------------------------------------------------------------
__global__ __launch_bounds__(256)
void chunk_all(const unsigned short* __restrict__ Qb, const unsigned short* __restrict__ Kb,
               const unsigned short* __restrict__ Vb, const float* __restrict__ rho,
               unsigned short* __restrict__ Yb)
{
  __shared__ __align__(16) unsigned short qs[2][4096];
  __shared__ __align__(16) unsigned short ks2[2][4096];
  __shared__ __align__(16) unsigned short vs2[2][4096];
  __shared__ __align__(16) unsigned short kt[64 * 72];  // K^T
  __shared__ __align__(16) unsigned short vt[64 * 72];  // V^T
  __shared__ __align__(16) unsigned short pt[64 * 72];  // Pw
  __shared__ __align__(16) unsigned short ssb[64 * 72]; // S^T bf16 shadow
  __shared__ __align__(16) float rho_all[1024];
  __shared__ float aw[64], cw[64], scs[64];
  const int tid = threadIdx.x;
  const int bh = blockIdx.x;
  const int b = bh >> 4, h = bh & 15;
  const int lane = tid & 63, wave = tid >> 6;
  const int quad = lane >> 4, tm = lane & 15;
  const int trow = 16 * wave + tm;

  // init: stage chunk 0 + full rho row; zero S shadow + regs
  stage_chunk_x(Qb, b * 1024, h, qs[0], tid);
  stage_chunk_x(Kb, b * 1024, h, ks2[0], tid);
  stage_chunk_x(Vb, b * 1024, h, vs2[0], tid);
  g2l16(rho + (size_t)bh * 1024 + tid * 4, rho_all + tid * 4);
  {
    unsigned* z = (unsigned*)ssb;
#pragma unroll
    for (int i = 0; i < 9; ++i) z[i * 256 + tid] = 0u;
  }
  float Sreg[4][4];
#pragma unroll
  for (int j4 = 0; j4 < 4; ++j4)
#pragma unroll
    for (int r = 0; r < 4; ++r) Sreg[j4][r] = 0.f;

  for (int c = 0; c < 16; ++c) {
    const int cur = c & 1;
    __syncthreads();   // drains staged buf[cur] DMA; ss writes from prev chunk
    if (c < 15) {
      const int n0n = b * 1024 + (c + 1) * 64;
      stage_chunk_x(Qb, n0n, h, qs[cur ^ 1], tid);
      stage_chunk_x(Kb, n0n, h, ks2[cur ^ 1], tid);
      stage_chunk_x(Vb, n0n, h, vs2[cur ^ 1], tid);
    }
    // wave0: rho prefix products
    if (tid < 64) {
      const float r = rho_all[c * 64 + tid];
      float p = r;
#pragma unroll
      for (int d = 1; d < 64; d <<= 1) {
        float o = __shfl_up(p, d);
        if (tid >= d) p *= o;
      }
      aw[tid] = p;
      const float cv = (1.f - r) / p;
      cw[tid] = cv;
      scs[tid] = __shfl(p, 63) * cv;   // A_c * (1-rho_s)/a_s
    }
    transpose_x(ks2[cur], kt, tid);
    transpose_x(vs2[cur], vt, tid);
    __syncthreads();   // kt, vt, aw/cw/scs ready

    // Phase A: P = Q V^T, mask -> pt (wave-private rows)
    b16x8 af_q[2];
#pragma unroll
    for (int kk = 0; kk < 2; ++kk)
      af_q[kk] = rdx(qs[cur], trow, kk * 32 + quad * 8);
#pragma unroll
    for (int j4 = 0; j4 < 4; ++j4) {
      f32x4 acc = (f32x4){0.f, 0.f, 0.f, 0.f};
#pragma unroll
      for (int kk = 0; kk < 2; ++kk) {
        const b16x8 bf = rdx(vs2[cur], 16 * j4 + tm, kk * 32 + quad * 8);
        acc = __builtin_amdgcn_mfma_f32_16x16x32_bf16(af_q[kk], bf, acc, 0, 0, 0);
      }
      const int s = 16 * j4 + tm;
      const float cws = cw[s];
#pragma unroll
      for (int r = 0; r < 4; ++r) {
        const int t = 16 * wave + quad * 4 + r;
        const float w = (s <= t) ? aw[t] * cws : 0.f;
        ((__bf16*)pt)[t * 72 + s] = (__bf16)(acc[r] * w);
      }
    }

    // fragments: scaled Q (a_t q_t), P, scaled K^T (for U)
    const float at = aw[trow];
    b16x8 af_qs[2], af_p[2], af_ks[2];
#pragma unroll
    for (int kk = 0; kk < 2; ++kk) {
      b16x8 t8;
#pragma unroll
      for (int j = 0; j < 8; ++j) t8[j] = (__bf16)(at * (float)af_q[kk][j]);
      af_qs[kk] = t8;
      af_p[kk] = *(const b16x8*)&pt[trow * 72 + kk * 32 + quad * 8];
      const int kbase = kk * 32 + quad * 8;
      const b16x8 kraw = *(const b16x8*)&kt[trow * 72 + kbase];
      b16x8 k8;
#pragma unroll
      for (int j = 0; j < 8; ++j) k8[j] = (__bf16)(scs[kbase + j] * (float)kraw[j]);
      af_ks[kk] = k8;
    }

    // Phase B: Y + U accumulators
    const int n0c = b * 1024 + c * 64;
    f32x4 Uacc[4];
#pragma unroll
    for (int j4 = 0; j4 < 4; ++j4) {
      const int kc = 16 * j4 + tm;
      f32x4 yacc = (f32x4){0.f, 0.f, 0.f, 0.f};
      f32x4 uacc = (f32x4){0.f, 0.f, 0.f, 0.f};
#pragma unroll
      for (int kk = 0; kk < 2; ++kk) {
        const int kbase = kk * 32 + quad * 8;
        const b16x8 bk = *(const b16x8*)&kt[kc * 72 + kbase];
        const b16x8 bs = *(const b16x8*)&ssb[kc * 72 + kbase];
        const b16x8 bv = *(const b16x8*)&vt[kc * 72 + kbase];
        yacc = __builtin_amdgcn_mfma_f32_16x16x32_bf16(af_p[kk],  bk, yacc, 0, 0, 0);
        yacc = __builtin_amdgcn_mfma_f32_16x16x32_bf16(af_qs[kk], bs, yacc, 0, 0, 0);
        uacc = __builtin_amdgcn_mfma_f32_16x16x32_bf16(af_ks[kk], bv, uacc, 0, 0, 0);
      }
      Uacc[j4] = uacc;
#pragma unroll
      for (int r = 0; r < 4; ++r) {
        const int t = 16 * wave + quad * 4 + r;
        Yb[(size_t)(n0c + t) * 1024 + h * 64 + kc] = f2b(yacc[r]);
      }
    }

    __syncthreads();   // all ssb reads (phase B) complete before update
    const float Ac = aw[63];
#pragma unroll
    for (int j4 = 0; j4 < 4; ++j4)
#pragma unroll
      for (int r = 0; r < 4; ++r) {
        const float sn = Ac * Sreg[j4][r] + Uacc[j4][r];
        Sreg[j4][r] = sn;
        const int kc = 16 * wave + quad * 4 + r;
        ssb[kc * 72 + 16 * j4 + tm] = f2b(sn);
      }
  }
}

// ---------------------------------------------------------------------------
extern "C" void kernel_launch(void* const* d_in, const int* in_sizes, int n_in,
                              void* d_out, int out_size, void* d_ws, size_t ws_size,
                              hipStream_t stream) {
  const void* x  = d_in[0];
  const void* Wq = d_in[1];
  const void* Wk = d_in[2];
  const void* Wv = d_in[3];
  const void* Wo = d_in[4];

  char* ws = (char*)d_ws;
  const size_t MB = 1ull << 20;
  unsigned short* x_b  = (unsigned short*)(ws);
  unsigned short* Wq_b = (unsigned short*)(ws + 8 * MB);
  unsigned short* Wk_b = (unsigned short*)(ws + 10 * MB);
  unsigned short* Wv_b = (unsigned short*)(ws + 12 * MB);
  unsigned short* Wo_b = (unsigned short*)(ws + 14 * MB);
  unsigned short* Qb = (unsigned short*)(ws + 16 * MB);
  unsigned short* Kb = (unsigned short*)(ws + 24 * MB);
  unsigned short* Vb = (unsigned short*)(ws + 32 * MB);
  unsigned short* Yb = (unsigned short*)(ws + 40 * MB);
  float*  rh   = (float*)(ws + 72 * MB);

  dim3 blk(256);
  convert_all<<<dim3(4096), blk, 0, stream>>>(x, Wq, Wk, Wv, Wo,
                                              x_b, Wq_b, Wk_b, Wv_b, Wo_b);
  gemm_qkv<<<dim3(768), blk, 0, stream>>>((const unsigned*)x,
      (const bf16_t*)x_b, (const bf16_t*)Wq_b, (const bf16_t*)Wk_b, (const bf16_t*)Wv_b,
      Qb, Kb, Vb, d_in[5], d_in[6], d_in[7], d_in[8], rh);
  chunk_all<<<dim3(64), blk, 0, stream>>>(Qb, Kb, Vb, rh, Yb);
  gemm_out64<<<dim3(1024), blk, 0, stream>>>((const unsigned*)x,
      (const bf16_t*)Yb, (const bf16_t*)Wo_b, d_out);
}

// Round 7
// 164.338 us; speedup vs baseline: 1.1565x; 1.1565x over previous
//
#include <hip/hip_runtime.h>
#include <hip/hip_bf16.h>

// STPT-Light: x->(Q,K,V) proj (fused K-norm+rho), chunked linear-attn (MFMA trio), out proj.
// B=4 T=1024 D=1024 H=16 DK=64. Chunk C=64, 16 chunks, 64 (b,h) pairs.
// R7 = R5 structure (chunk trio) + R6's BK=64 gemm_qkv. Fusion of the trio
// regressed (R6: 64 blocks -> 2.5% occupancy); parallel passes must span the chip.
//
// ws layout (MB): 0 x_b[8] | 8 Wq_b[2] 10 Wk_b[2] 12 Wv_b[2] 14 Wo_b[2]
//   16 Qb[8] 24 Kb[8] 32 Vb[8] 40 Yb[8]  (bf16 4096x1024)
//   48 Ug[8] (bf16 U^T) | 64 Sp[8] (bf16 S^T snapshots)
//   72 rho[256KB f32] | +256KB A_g[4KB]

typedef __bf16 b16x8 __attribute__((ext_vector_type(8)));
typedef float  f32x4 __attribute__((ext_vector_type(4)));
typedef unsigned short u16x8 __attribute__((ext_vector_type(8)));
using bf16_t = __hip_bfloat16;

#define AS1C(p) ((const __attribute__((address_space(1))) void*)(p))
#define AS3(p)  ((__attribute__((address_space(3))) void*)(p))

__device__ __forceinline__ void g2l16(const void* g, void* l) {
  __builtin_amdgcn_global_load_lds(AS1C(g), AS3(l), 16, 0, 0);
}
__device__ __forceinline__ void g2l4(const void* g, void* l) {
  __builtin_amdgcn_global_load_lds(AS1C(g), AS3(l), 4, 0, 0);
}

__device__ __forceinline__ unsigned short f2b(float x) {  // RNE f32->bf16 bits
  unsigned u = __float_as_uint(x);
  return (unsigned short)((u + 0x7FFFu + ((u >> 16) & 1u)) >> 16);
}
__device__ __forceinline__ float b2f(unsigned short b) {
  return __uint_as_float(((unsigned)b) << 16);
}

// Wire-format detector: f32 N(0,1) words have exponent field in [95,135].
__device__ __forceinline__ int wire_flag(const unsigned* __restrict__ x, int tid) {
  unsigned u = x[tid & 63];
  int e = (int)((u >> 23) & 0xFF);
  unsigned long long m = __ballot(e >= 95 && e <= 135);
  return (__popcll(m) >= 32) ? 1 : 0;   // 1 = f32 wire
}

// ---------------------------------------------------------------------------
// Fused conversion of all 5 input tensors to bf16 (or passthrough copy).
// ---------------------------------------------------------------------------
__global__ __launch_bounds__(256)
void convert_all(const void* __restrict__ x,
                 const void* __restrict__ w0, const void* __restrict__ w1,
                 const void* __restrict__ w2, const void* __restrict__ w3,
                 unsigned short* __restrict__ xb,
                 unsigned short* __restrict__ wb0, unsigned short* __restrict__ wb1,
                 unsigned short* __restrict__ wb2, unsigned short* __restrict__ wb3)
{
  const int fm = wire_flag((const unsigned*)x, threadIdx.x);
  const long i8 = ((long)blockIdx.x * 256 + threadIdx.x) * 8;
  const void* src; unsigned short* dst; long off;
  if (i8 < 4194304) { src = x; dst = xb; off = i8; }
  else {
    long j = i8 - 4194304;
    int w = (int)(j >> 20); off = j & 1048575;
    src = (w == 0) ? w0 : (w == 1) ? w1 : (w == 2) ? w2 : w3;
    dst = (w == 0) ? wb0 : (w == 1) ? wb1 : (w == 2) ? wb2 : wb3;
  }
  if (fm) {
    const float4 a = *(const float4*)((const float*)src + off);
    const float4 b = *(const float4*)((const float*)src + off + 4);
    u16x8 o;
    o[0] = f2b(a.x); o[1] = f2b(a.y); o[2] = f2b(a.z); o[3] = f2b(a.w);
    o[4] = f2b(b.x); o[5] = f2b(b.y); o[6] = f2b(b.z); o[7] = f2b(b.w);
    *(u16x8*)(dst + off) = o;
  } else {
    *(int4*)(dst + off) = *(const int4*)((const unsigned short*)src + off);
  }
}

// ---------------------------------------------------------------------------
// Fused Q/K/V projection. 128x128 tile, BK=64 (32 MFMA per barrier pair),
// XOR source swizzle, XCD patch decode. z==1 (K): epilogue L2-norm + rho.
// ---------------------------------------------------------------------------
__global__ __launch_bounds__(256)
void gemm_qkv(const unsigned* __restrict__ xraw,
              const bf16_t* __restrict__ A,
              const bf16_t* __restrict__ B0, const bf16_t* __restrict__ B1,
              const bf16_t* __restrict__ B2,
              unsigned short* __restrict__ C0, unsigned short* __restrict__ C1,
              unsigned short* __restrict__ C2,
              const void* __restrict__ Wg, const void* __restrict__ bg,
              const void* __restrict__ Wl, const void* __restrict__ bl,
              float* __restrict__ rho)
{
  constexpr int K = 1024, N = 1024;
  const int flat = blockIdx.x;
  const int xcd = flat & 7, sl = flat >> 3;
  const int z = sl >> 5, t5 = sl & 31;
  const int bx = ((xcd & 1) << 2) | (t5 & 3);
  const int by = ((xcd >> 1) << 3) | (t5 >> 2);
  const bf16_t* B = (z == 0) ? B0 : (z == 1) ? B1 : B2;
  unsigned short* C = (z == 0) ? C0 : (z == 1) ? C1 : C2;
  __shared__ __align__(16) unsigned short As[128 * 64];
  __shared__ __align__(16) unsigned short Bs[128 * 64];
  const int tid  = threadIdx.x;
  const int lane = tid & 63;
  const int wave = tid >> 6;
  const int wm = wave >> 1, wn = wave & 1;
  const int quad = lane >> 4, tm = lane & 15;
  const long row0 = (long)by * 128;
  const long col0 = (long)bx * 128;

  f32x4 acc[4][4];
#pragma unroll
  for (int i = 0; i < 4; ++i)
#pragma unroll
    for (int j = 0; j < 4; ++j) acc[i][j] = (f32x4){0.f, 0.f, 0.f, 0.f};

  const int sr = tid >> 3;            // 0..31 (+32/shot)
  const int c2 = tid & 7;
  const int gc = c2 ^ (sr & 7);
  const bf16_t* ap = A + (row0 + sr) * (long)K + gc * 8;
  const bf16_t* bp = B + (col0 + sr) * (long)K + gc * 8;
  unsigned short* la = As + tid * 8;
  unsigned short* lb = Bs + tid * 8;

  for (int kt = 0; kt < K; kt += 64) {
    __syncthreads();
#pragma unroll
    for (int sh = 0; sh < 4; ++sh) {
      g2l16(ap + (long)sh * 32 * K + kt, la + sh * 2048);
      g2l16(bp + (long)sh * 32 * K + kt, lb + sh * 2048);
    }
    __syncthreads();

#pragma unroll
    for (int kk = 0; kk < 2; ++kk) {
      const int pcsel = ((kk * 4 + quad) ^ (tm & 7)) << 3;
      b16x8 af[4], bfr[4];
#pragma unroll
      for (int i = 0; i < 4; ++i)
        af[i] = *(const b16x8*)&As[(wm * 64 + i * 16 + tm) * 64 + pcsel];
#pragma unroll
      for (int j = 0; j < 4; ++j)
        bfr[j] = *(const b16x8*)&Bs[(wn * 64 + j * 16 + tm) * 64 + pcsel];
#pragma unroll
      for (int i = 0; i < 4; ++i)
#pragma unroll
        for (int j = 0; j < 4; ++j)
          acc[i][j] = __builtin_amdgcn_mfma_f32_16x16x32_bf16(af[i], bfr[j], acc[i][j], 0, 0, 0);
    }
  }

  if (z != 1) {
#pragma unroll
    for (int i = 0; i < 4; ++i)
#pragma unroll
      for (int j = 0; j < 4; ++j)
#pragma unroll
        for (int r = 0; r < 4; ++r) {
          long row = row0 + wm * 64 + i * 16 + quad * 4 + r;
          long col = col0 + wn * 64 + j * 16 + tm;
          C[row * N + col] = f2b(acc[i][j][r]);
        }
  } else {
    const int fm = wire_flag(xraw, tid);
    const int h = bx * 2 + wn;
    float wgv, bgv, wlv, blv;
    if (fm) {
      wgv = ((const float*)Wg)[h]; bgv = ((const float*)bg)[h];
      wlv = ((const float*)Wl)[h]; blv = ((const float*)bl)[h];
    } else {
      wgv = b2f(((const unsigned short*)Wg)[h]); bgv = b2f(((const unsigned short*)bg)[h]);
      wlv = b2f(((const unsigned short*)Wl)[h]); blv = b2f(((const unsigned short*)bl)[h]);
    }
#pragma unroll
    for (int i = 0; i < 4; ++i)
#pragma unroll
      for (int r = 0; r < 4; ++r) {
        float ss = 0.f, sv = 0.f;
#pragma unroll
        for (int j = 0; j < 4; ++j) {
          const float v = acc[i][j][r];
          ss += v * v; sv += v;
        }
#pragma unroll
        for (int m = 1; m < 16; m <<= 1) {
          ss += __shfl_xor(ss, m);
          sv += __shfl_xor(sv, m);
        }
        const float inv = 1.f / fmaxf(sqrtf(ss), 1e-12f);
        const long row = row0 + wm * 64 + i * 16 + quad * 4 + r;
#pragma unroll
        for (int j = 0; j < 4; ++j)
          C[row * N + col0 + wn * 64 + j * 16 + tm] = f2b(acc[i][j][r] * inv);
        if (tm == 0) {
          const float kbar = sv * inv * (1.f / 64.f);
          const float gm = 1.f / (1.f + expf(-(wgv * kbar + bgv)));
          const float lm = 1.f / (1.f + expf(-(wlv * kbar + blv)));
          const int b = (int)(row >> 10), t = (int)(row & 1023);
          rho[(size_t)(b * 16 + h) * 1024 + t] = (1.f - lm) * gm;
        }
      }
  }
}

// ---------------------------------------------------------------------------
// Output GEMM: 64x64 tile, BK=64, XCD patch decode.
// ---------------------------------------------------------------------------
__global__ __launch_bounds__(256)
void gemm_out64(const unsigned* __restrict__ xraw,
                const bf16_t* __restrict__ A, const bf16_t* __restrict__ B,
                void* __restrict__ C)
{
  constexpr int K = 1024, N = 1024;
  const int flat = blockIdx.x;
  const int xcd = flat & 7, sl = flat >> 3;
  const int bx = sl & 15;
  const int by = (xcd << 3) | (sl >> 4);
  __shared__ __align__(16) unsigned short As[64 * 64];
  __shared__ __align__(16) unsigned short Bs[64 * 64];
  const int tid  = threadIdx.x;
  const int lane = tid & 63;
  const int wave = tid >> 6;
  const int quad = lane >> 4, tm = lane & 15;
  const long row0 = (long)by * 64;
  const long col0 = (long)bx * 64;

  f32x4 acc[4];
#pragma unroll
  for (int i = 0; i < 4; ++i) acc[i] = (f32x4){0.f, 0.f, 0.f, 0.f};

  const int sr = tid >> 2;
  const int scc = tid & 3;
  const int qg = (scc - (sr >> 1)) & 3;
  const bf16_t* ap = A + (row0 + sr) * (long)K + qg * 8;
  const bf16_t* bp = B + (col0 + sr) * (long)K + qg * 8;
  unsigned short* la = As + tid * 8;
  unsigned short* lb = Bs + tid * 8;
  const int cc = (quad + ((tm >> 1) & 3)) & 3;

  for (int kt = 0; kt < K; kt += 64) {
    __syncthreads();
    g2l16(ap + kt,      la);
    g2l16(ap + kt + 32, la + 2048);
    g2l16(bp + kt,      lb);
    g2l16(bp + kt + 32, lb + 2048);
    __syncthreads();

    b16x8 bf0 = *(const b16x8*)&Bs[(wave * 16 + tm) * 32 + cc * 8];
    b16x8 bf1 = *(const b16x8*)&Bs[2048 + (wave * 16 + tm) * 32 + cc * 8];
#pragma unroll
    for (int i = 0; i < 4; ++i) {
      b16x8 a0 = *(const b16x8*)&As[(i * 16 + tm) * 32 + cc * 8];
      b16x8 a1 = *(const b16x8*)&As[2048 + (i * 16 + tm) * 32 + cc * 8];
      acc[i] = __builtin_amdgcn_mfma_f32_16x16x32_bf16(a0, bf0, acc[i], 0, 0, 0);
      acc[i] = __builtin_amdgcn_mfma_f32_16x16x32_bf16(a1, bf1, acc[i], 0, 0, 0);
    }
  }

  const int fm = wire_flag(xraw, tid);
#pragma unroll
  for (int i = 0; i < 4; ++i)
#pragma unroll
    for (int r = 0; r < 4; ++r) {
      const long row = row0 + i * 16 + quad * 4 + r;
      const long col = col0 + wave * 16 + tm;
      const float v = acc[i][r];
      if (fm) ((float*)C)[row * N + col] = v;
      else    ((unsigned short*)C)[row * N + col] = f2b(v);
    }
}

// ---------------------------------------------------------------------------
// XOR-swizzled chunk staging + reads (conflict-free).
// ---------------------------------------------------------------------------
__device__ __forceinline__ void stage_chunk_x(const unsigned short* G, int n0c, int h,
                                              unsigned short* lds, int tid) {
#pragma unroll
  for (int sh = 0; sh < 2; ++sh) {
    const int idx = sh * 256 + tid;
    const int row = idx >> 3, c2 = idx & 7;
    const int gc = c2 ^ (row & 7);
    g2l16(G + (size_t)(n0c + row) * 1024 + h * 64 + gc * 8, lds + idx * 8);
  }
}
__device__ __forceinline__ void stage_blk_x(const unsigned short* G,
                                            unsigned short* lds, int tid) {
#pragma unroll
  for (int sh = 0; sh < 2; ++sh) {
    const int idx = sh * 256 + tid;
    const int row = idx >> 3, c2 = idx & 7;
    const int gc = c2 ^ (row & 7);
    g2l16(G + row * 64 + gc * 8, lds + idx * 8);
  }
}
__device__ __forceinline__ b16x8 rdx(const unsigned short* lds, int row, int k0) {
  return *(const b16x8*)&lds[row * 64 + (((k0 >> 3) ^ (row & 7)) << 3)];
}
__device__ __forceinline__ float rdx1(const unsigned short* lds, int row, int col) {
  return b2f(lds[row * 64 + (((col >> 3) ^ (row & 7)) << 3) + (col & 7)]);
}

// dst[col][row] (stride 72 bf16) from XOR-staged src[row][col], optional row scale.
__device__ __forceinline__ void transpose_x(const unsigned short* src,
                                            unsigned short* dst,
                                            const float* sc, int tid) {
  const int kc = tid & 63;
  const int s4 = (tid >> 6) * 16;
  u16x8 o0, o1;
#pragma unroll
  for (int i = 0; i < 16; ++i) {
    const int s = s4 + i;
    float v = rdx1(src, s, kc);
    if (sc) v *= sc[s];
    const unsigned short b = f2b(v);
    if (i < 8) o0[i] = b; else o1[i - 8] = b;
  }
  *(u16x8*)&dst[kc * 72 + s4]     = o0;
  *(u16x8*)&dst[kc * 72 + s4 + 8] = o1;
}

// Wave-0 prefix product: aw=a_t, cw=(1-rho)/a, sc=A_c*(1-rho)/a.
__device__ __forceinline__ void rho_scan(const float* rho_s, float* aw, float* cw,
                                         float* sc, int tid) {
  if (tid < 64) {
    const float r = rho_s[tid];
    float p = r;
#pragma unroll
    for (int d = 1; d < 64; d <<= 1) {
      float o = __shfl_up(p, d);
      if (tid >= d) p *= o;
    }
    aw[tid] = p;
    const float c = (1.f - r) / p;
    cw[tid] = c;
    const float Ac = __shfl(p, 63);
    sc[tid] = Ac * c;
  }
}

// ---------------------------------------------------------------------------
// Pass 1: U^T[kc][v] = sum_s sc[s]*k_s[kc]*v_s[v] via Ktilde^T * V. 1024 blocks.
// ---------------------------------------------------------------------------
__global__ __launch_bounds__(256)
void chunk_outer(const unsigned short* __restrict__ Kb, const unsigned short* __restrict__ Vb,
                 const float* __restrict__ rho, unsigned short* __restrict__ Ug,
                 float* __restrict__ A_g)
{
  __shared__ __align__(16) unsigned short ks[4096];
  __shared__ __align__(16) unsigned short vs[4096];
  __shared__ __align__(16) unsigned short kt[64 * 72];
  __shared__ __align__(16) unsigned short vt[64 * 72];
  __shared__ float rho_s[64], aw[64], cw[64], sc[64];
  const int tid = threadIdx.x;
  const int bid = blockIdx.x;
  const int bh = bid >> 4, c = bid & 15;
  const int b = bh >> 4, h = bh & 15;
  const int n0c = b * 1024 + c * 64;
  const int lane = tid & 63, wave = tid >> 6;
  const int quad = lane >> 4, tm = lane & 15;

  stage_chunk_x(Kb, n0c, h, ks, tid);
  stage_chunk_x(Vb, n0c, h, vs, tid);
  if (tid < 64) g2l4(rho + (size_t)bh * 1024 + c * 64 + tid, rho_s + tid);
  __syncthreads();
  rho_scan(rho_s, aw, cw, sc, tid);
  __syncthreads();
  transpose_x(ks, kt, sc, tid);      // Ktilde^T (scaled)
  transpose_x(vs, vt, nullptr, tid); // V^T
  __syncthreads();

  const int mrow = 16 * wave + tm;
  b16x8 a0 = *(const b16x8*)&kt[mrow * 72 + quad * 8];
  b16x8 a1 = *(const b16x8*)&kt[mrow * 72 + 32 + quad * 8];
#pragma unroll
  for (int j4 = 0; j4 < 4; ++j4) {
    const int nrow = 16 * j4 + tm;
    b16x8 b0 = *(const b16x8*)&vt[nrow * 72 + quad * 8];
    b16x8 b1 = *(const b16x8*)&vt[nrow * 72 + 32 + quad * 8];
    f32x4 acc = (f32x4){0.f, 0.f, 0.f, 0.f};
    acc = __builtin_amdgcn_mfma_f32_16x16x32_bf16(a0, b0, acc, 0, 0, 0);
    acc = __builtin_amdgcn_mfma_f32_16x16x32_bf16(a1, b1, acc, 0, 0, 0);
#pragma unroll
    for (int r = 0; r < 4; ++r) {
      const int kc = 16 * wave + quad * 4 + r;
      Ug[(size_t)bid * 4096 + kc * 64 + 16 * j4 + tm] = f2b(acc[r]);
    }
  }
  if (tid == 0) A_g[bid] = aw[63];
}

// ---------------------------------------------------------------------------
// Pass 2: elementwise chunk scan in transposed layout. 1024 blocks.
// ---------------------------------------------------------------------------
__global__ __launch_bounds__(256)
void chunk_scan(const unsigned short* __restrict__ Ug, const float* __restrict__ A_g,
                unsigned short* __restrict__ Sp)
{
  const int bh = blockIdx.x >> 4;
  const int e  = (blockIdx.x & 15) * 256 + threadIdx.x;
  const size_t base = (size_t)bh * 16 * 4096 + e;
  float S = 0.f;
#pragma unroll
  for (int c = 0; c < 16; ++c) {
    Sp[base + (size_t)c * 4096] = f2b(S);
    S = A_g[bh * 16 + c] * S + b2f(Ug[base + (size_t)c * 4096]);
  }
}

// ---------------------------------------------------------------------------
// Pass 3: P = Q V^T (masked), Y = Pw*K + diag(a_t) Q S_prev. 1024 blocks.
// ---------------------------------------------------------------------------
__global__ __launch_bounds__(256)
void chunk_y(const unsigned short* __restrict__ Qb, const unsigned short* __restrict__ Kb,
             const unsigned short* __restrict__ Vb, const unsigned short* __restrict__ Sp,
             const float* __restrict__ rho, unsigned short* __restrict__ Yb)
{
  __shared__ __align__(16) unsigned short qs[4096];
  __shared__ __align__(16) unsigned short ks[4096];
  __shared__ __align__(16) unsigned short vs[4096];
  __shared__ __align__(16) unsigned short ss[4096];   // S^T, XOR-staged
  __shared__ __align__(16) unsigned short kt[64 * 72]; // K^T
  __shared__ __align__(16) unsigned short pt[64 * 72]; // Pw
  __shared__ float rho_s[64], aw[64], cw[64], sc[64];
  const int tid = threadIdx.x;
  const int bid = blockIdx.x;
  const int bh = bid >> 4, c = bid & 15;
  const int b = bh >> 4, h = bh & 15;
  const int n0c = b * 1024 + c * 64;
  const int lane = tid & 63, wave = tid >> 6;
  const int quad = lane >> 4, tm = lane & 15;

  stage_chunk_x(Qb, n0c, h, qs, tid);
  stage_chunk_x(Kb, n0c, h, ks, tid);
  stage_chunk_x(Vb, n0c, h, vs, tid);
  stage_blk_x(Sp + (size_t)bid * 4096, ss, tid);
  if (tid < 64) g2l4(rho + (size_t)bh * 1024 + c * 64 + tid, rho_s + tid);
  __syncthreads();
  rho_scan(rho_s, aw, cw, sc, tid);
  __syncthreads();
  transpose_x(ks, kt, nullptr, tid);   // K^T for phase B (barrier below)

  __bf16* ptb = (__bf16*)pt;
  const int trow = 16 * wave + tm;

  // Phase A: P tiles + mask -> pt (wave-private rows, stride 72)
  b16x8 af_q[2];
#pragma unroll
  for (int kk = 0; kk < 2; ++kk)
    af_q[kk] = rdx(qs, trow, kk * 32 + quad * 8);
#pragma unroll
  for (int j4 = 0; j4 < 4; ++j4) {
    f32x4 acc = (f32x4){0.f, 0.f, 0.f, 0.f};
#pragma unroll
    for (int kk = 0; kk < 2; ++kk) {
      const b16x8 bf = rdx(vs, 16 * j4 + tm, kk * 32 + quad * 8);
      acc = __builtin_amdgcn_mfma_f32_16x16x32_bf16(af_q[kk], bf, acc, 0, 0, 0);
    }
    const int s = 16 * j4 + tm;
    const float cws = cw[s];
#pragma unroll
    for (int r = 0; r < 4; ++r) {
      const int t = 16 * wave + quad * 4 + r;
      const float w = (s <= t) ? aw[t] * cws : 0.f;
      ptb[t * 72 + s] = (__bf16)(acc[r] * w);
    }
  }

  const float at = aw[trow];
  b16x8 af_qs[2], af_p[2];
#pragma unroll
  for (int kk = 0; kk < 2; ++kk) {
    b16x8 t8;
#pragma unroll
    for (int j = 0; j < 8; ++j) t8[j] = (__bf16)(at * (float)af_q[kk][j]);
    af_qs[kk] = t8;
    af_p[kk] = *(const b16x8*)&pt[trow * 72 + kk * 32 + quad * 8];
  }
  __syncthreads();   // kt complete (pt rows are wave-private)

  // Phase B: Y[t][kc] = sum_s Pw[t][s] K[s][kc] + sum_v a_t q[t][v] S[v][kc]
#pragma unroll
  for (int j4 = 0; j4 < 4; ++j4) {
    const int kc = 16 * j4 + tm;
    f32x4 acc = (f32x4){0.f, 0.f, 0.f, 0.f};
#pragma unroll
    for (int kk = 0; kk < 2; ++kk) {
      const int kbase = kk * 32 + quad * 8;
      const b16x8 bk = *(const b16x8*)&kt[kc * 72 + kbase];
      const b16x8 bs = rdx(ss, kc, kbase);
      acc = __builtin_amdgcn_mfma_f32_16x16x32_bf16(af_p[kk],  bk, acc, 0, 0, 0);
      acc = __builtin_amdgcn_mfma_f32_16x16x32_bf16(af_qs[kk], bs, acc, 0, 0, 0);
    }
#pragma unroll
    for (int r = 0; r < 4; ++r) {
      const int t = 16 * wave + quad * 4 + r;
      Yb[(size_t)(n0c + t) * 1024 + h * 64 + kc] = f2b(acc[r]);
    }
  }
}

// ---------------------------------------------------------------------------
extern "C" void kernel_launch(void* const* d_in, const int* in_sizes, int n_in,
                              void* d_out, int out_size, void* d_ws, size_t ws_size,
                              hipStream_t stream) {
  const void* x  = d_in[0];
  const void* Wq = d_in[1];
  const void* Wk = d_in[2];
  const void* Wv = d_in[3];
  const void* Wo = d_in[4];

  char* ws = (char*)d_ws;
  const size_t MB = 1ull << 20;
  unsigned short* x_b  = (unsigned short*)(ws);
  unsigned short* Wq_b = (unsigned short*)(ws + 8 * MB);
  unsigned short* Wk_b = (unsigned short*)(ws + 10 * MB);
  unsigned short* Wv_b = (unsigned short*)(ws + 12 * MB);
  unsigned short* Wo_b = (unsigned short*)(ws + 14 * MB);
  unsigned short* Qb = (unsigned short*)(ws + 16 * MB);
  unsigned short* Kb = (unsigned short*)(ws + 24 * MB);
  unsigned short* Vb = (unsigned short*)(ws + 32 * MB);
  unsigned short* Yb = (unsigned short*)(ws + 40 * MB);
  unsigned short* Ug = (unsigned short*)(ws + 48 * MB);
  unsigned short* Sp = (unsigned short*)(ws + 64 * MB);
  float*  rh   = (float*)(ws + 72 * MB);
  float*  A_g  = (float*)(ws + 72 * MB + 256 * 1024);

  dim3 blk(256);
  convert_all<<<dim3(4096), blk, 0, stream>>>(x, Wq, Wk, Wv, Wo,
                                              x_b, Wq_b, Wk_b, Wv_b, Wo_b);
  gemm_qkv<<<dim3(768), blk, 0, stream>>>((const unsigned*)x,
      (const bf16_t*)x_b, (const bf16_t*)Wq_b, (const bf16_t*)Wk_b, (const bf16_t*)Wv_b,
      Qb, Kb, Vb, d_in[5], d_in[6], d_in[7], d_in[8], rh);
  chunk_outer<<<dim3(1024), blk, 0, stream>>>(Kb, Vb, rh, Ug, A_g);
  chunk_scan<<<dim3(1024), blk, 0, stream>>>(Ug, A_g, Sp);
  chunk_y<<<dim3(1024), blk, 0, stream>>>(Qb, Kb, Vb, Sp, rh, Yb);
  gemm_out64<<<dim3(1024), blk, 0, stream>>>((const unsigned*)x,
      (const bf16_t*)Yb, (const bf16_t*)Wo_b, d_out);
}